// Round 10
// baseline (257.534 us; speedup 1.0000x reference)
//
#include <hip/hip_runtime.h>
#include <hip/hip_bf16.h>

// CrossModalContrastiveLoss: B=8, C=256, H=W=32 -> N=8192 vectors of dim 256.
// loss = -( P - 1024 * sum_i log(sum_j exp(S_ij)) ) / 8388608,
// S = normalize(rgb) @ normalize(x)^T / 0.1.
// P analytic via bilinearity (verified r7-r9): P = ln2 * sum_b <rgbsum_b, xsum_b>
// where rgb side carries k2 = 10*log2(e) folded in at fp8 quantization
// (S_mfma = k2*sim, exp(10 sim) = exp2(S_mfma)).
//
// Round-10:
//  * xq stored PAIR-INTERLEAVED in K: 16-B unit u = 4t+q holds k-bytes
//    [ (8t+q)*8 , (8t+4+q)*8 ) pairs -> gemm reads B-fragments for s=2t,2t+1
//    with ONE ds_read_b128, swizzled slot = (4t+quad)^l15 (full 4-bit XOR:
//    every 16-lane group spans all 16 unit-slots -> 0 bank conflicts, the
//    pattern that measured 0 in the bf16 rounds).
//  * norm: float4 global loads (8 instrs/thread), inits sumexp/done, writes
//    per-block bpart partials (no atomics -> no pre-zeroing -> no memset
//    dispatch). 2 dispatches total.

#define HWsz 1024
#define Cdim 256
#define Nvec 8192
#define CHW  (Cdim * HWsz)
#define NBLK 1024   // 16 strips x 64 rowgroups

typedef __attribute__((ext_vector_type(4))) float f32x4;
typedef __attribute__((ext_vector_type(2))) long longx2;

// Block = 32 vectors (one batch), 256 threads: part = t>>3 (channel chunk of
// 8), q = t&7 (vector quad). float4 loads: lane reads 16 B contiguous.
__global__ __launch_bounds__(256) void norm_kernel(
    const float* __restrict__ rgb, const float* __restrict__ x,
    unsigned char* __restrict__ rgbq, unsigned char* __restrict__ xq,
    float* __restrict__ bpart, float* __restrict__ sumexp,
    unsigned int* __restrict__ done) {
  __shared__ float ssp[32][33];
  __shared__ __align__(16) unsigned char tile[32][272];  // 272 = 16*17
  const int t = threadIdx.x;
  const int part = t >> 3;      // channel chunk (8 channels)
  const int q = t & 7;          // vector quad (4 vectors)
  const int isx = blockIdx.y;
  const float* src = isx ? x : rgb;
  unsigned char* dst = isx ? xq : rgbq;
  const int n0 = blockIdx.x * 32;
  const int b = n0 >> 10;       // batch, uniform per block
  const int hw0 = n0 & 1023;
  const float* p =
      src + (size_t)b * CHW + (size_t)part * 8 * HWsz + hw0 + q * 4;

  // init gemm-side buffers (safe: gemm is stream-ordered after this kernel)
  if (isx == 0) {
    if (t < 32) sumexp[blockIdx.x * 32 + t] = 0.f;
    if (blockIdx.x == 0 && t == 0) done[0] = 0u;
  }

  // va[k][j]: vector q*4+k, channel part*8+j
  float va[4][8];
  float ss[4] = {0.f, 0.f, 0.f, 0.f};
#pragma unroll
  for (int j = 0; j < 8; ++j) {
    const float4 v4 = *reinterpret_cast<const float4*>(p + (size_t)j * HWsz);
    va[0][j] = v4.x; va[1][j] = v4.y; va[2][j] = v4.z; va[3][j] = v4.w;
    ss[0] += v4.x * v4.x; ss[1] += v4.y * v4.y;
    ss[2] += v4.z * v4.z; ss[3] += v4.w * v4.w;
  }
#pragma unroll
  for (int k = 0; k < 4; ++k) ssp[part][q * 4 + k] = ss[k];
  __syncthreads();

  const float k2 = 14.4269504089f;  // (1/T) * log2(e), folded into rgb side
  const float topf = isx ? 1.0f : k2;
#pragma unroll
  for (int k = 0; k < 4; ++k) {
    float tot = 0.f;
#pragma unroll
    for (int p2 = 0; p2 < 32; ++p2) tot += ssp[p2][q * 4 + k];
    const float inv = topf / fmaxf(sqrtf(tot), 1e-12f);
    int pk0 = 0, pk1 = 0;
    pk0 = __builtin_amdgcn_cvt_pk_fp8_f32(va[0][0] * inv, va[0][1] * inv, pk0, false);
    pk0 = __builtin_amdgcn_cvt_pk_fp8_f32(va[0][2] * inv, va[0][3] * inv, pk0, true);
    pk1 = __builtin_amdgcn_cvt_pk_fp8_f32(va[0][4] * inv, va[0][5] * inv, pk1, false);
    pk1 = __builtin_amdgcn_cvt_pk_fp8_f32(va[0][6] * inv, va[0][7] * inv, pk1, true);
    // shift va rows down so va[0] is always the active k (keeps indices const)
#pragma unroll
    for (int kk = 0; kk < 3; ++kk)
#pragma unroll
      for (int j = 0; j < 8; ++j) va[kk][j] = va[kk + 1][j];
    unsigned int* wp =
        reinterpret_cast<unsigned int*>(&tile[q * 4 + k][part * 8]);
    wp[0] = (unsigned int)pk0;
    wp[1] = (unsigned int)pk1;
  }
  __syncthreads();

  // store: 2 passes x (16 rows x 256 B). xq gets the pair-interleaved K
  // permutation: unit u holds natural pieces p0 = 8*(u>>2)+(u&3) and p0+4.
#pragma unroll
  for (int pass = 0; pass < 2; ++pass) {
    const int r = pass * 16 + (t >> 4);
    const int u = t & 15;
    if (isx) {
      const int p0 = 8 * (u >> 2) + (u & 3);
      longx2 val;
      val.x = *reinterpret_cast<const long*>(&tile[r][p0 * 8]);
      val.y = *reinterpret_cast<const long*>(&tile[r][(p0 + 4) * 8]);
      *reinterpret_cast<longx2*>(dst + (size_t)(n0 + r) * Cdim + u * 16) = val;
    } else {
      *reinterpret_cast<uint4*>(dst + (size_t)(n0 + r) * Cdim + u * 16) =
          *reinterpret_cast<const uint4*>(&tile[r][u * 16]);
    }
  }

  // per-channel column partial over this block's 32 vectors (dequantized =
  // exactly what the MFMA consumes). Plain store -> no init needed.
  float csum = 0.f;
#pragma unroll
  for (int r = 0; r < 32; ++r)
    csum += __builtin_amdgcn_cvt_f32_fp8((int)tile[r][t], 0);
  bpart[((size_t)isx * 256 + blockIdx.x) * 256 + t] = csum;
}

// Block = 4 waves, 128 rows x 512-col strip, fp8. A-panel 32 regs/wave
// (natural layout, direct b64 loads). B: 8 chunks of 64 cols through
// double-buffered 2x16 KB LDS; staging slot vv holds permuted-global unit
// vv ^ (col&15); reader slot = (4t+quad) ^ l15 -> ds_read_b128 gives the
// s=2t (lo) and s=2t+1 (hi) fragments. 4 blocks/CU.
__global__ __launch_bounds__(256, 4) void gemm_loss_kernel(
    const unsigned char* __restrict__ A, const unsigned char* __restrict__ Bq,
    float* __restrict__ sumexp, const float* __restrict__ bpart,
    unsigned int* __restrict__ done, float* __restrict__ out) {
  __shared__ __align__(16) unsigned char sB[2][16384];
  __shared__ float part4[4], part4b[4];
  __shared__ unsigned int is_last;

  const int tid  = threadIdx.x;
  const int lane = tid & 63;
  const int w    = tid >> 6;      // wave 0..3 -> rows w*32..+32
  const int strip = blockIdx.x;   // 0..15 -> XCD-pinned (linear%8 == x%8)
  const int rg   = blockIdx.y;    // 0..63: rows rg*128..+128
  const int quad = lane >> 4;
  const int l15  = lane & 15;

  // ---- A fragments: direct global -> 32 regs/wave, once per block ----
  long areg[8][2];
#pragma unroll
  for (int mi = 0; mi < 2; ++mi) {
    const unsigned char* rp =
        A + (size_t)(rg * 128 + w * 32 + mi * 16 + l15) * Cdim + quad * 8;
#pragma unroll
    for (int s = 0; s < 8; ++s)
      areg[s][mi] = *reinterpret_cast<const long*>(rp + s * 32);
  }

  const int colOff = lane >> 4;   // staging: col within 4-col group
  const int vv = lane & 15;       // staging: LDS 16-B slot

  float rowexp[8];
#pragma unroll
  for (int i = 0; i < 8; ++i) rowexp[i] = 0.f;

  const unsigned char* Bbase = Bq + (size_t)strip * 512 * Cdim;

  // prefetch chunk 0
#pragma unroll
  for (int i = 0; i < 4; ++i) {
    const int colw = w * 16 + i * 4 + colOff;
    const unsigned char* gp =
        Bbase + (size_t)colw * Cdim + ((vv ^ (colw & 15)) * 16);
    unsigned char* lp = &sB[0][(w * 16 + i * 4) * 256];
    __builtin_amdgcn_global_load_lds(
        (const __attribute__((address_space(1))) void*)gp,
        (__attribute__((address_space(3))) void*)lp, 16, 0, 0);
  }
  __syncthreads();

  for (int c = 0; c < 8; ++c) {
    const int bf = c & 1;
    if (c < 7) {  // prefetch next chunk (overlaps this chunk's MFMA)
#pragma unroll
      for (int i = 0; i < 4; ++i) {
        const int colw = w * 16 + i * 4 + colOff;
        const unsigned char* gp =
            Bbase + (size_t)((c + 1) * 64 + colw) * Cdim +
            ((vv ^ (colw & 15)) * 16);
        unsigned char* lp = &sB[bf ^ 1][(w * 16 + i * 4) * 256];
        __builtin_amdgcn_global_load_lds(
            (const __attribute__((address_space(1))) void*)gp,
            (__attribute__((address_space(3))) void*)lp, 16, 0, 0);
      }
    }

    f32x4 acc[2][4];
#pragma unroll
    for (int mi = 0; mi < 2; ++mi)
#pragma unroll
      for (int ni = 0; ni < 4; ++ni) acc[mi][ni] = (f32x4){0.f, 0.f, 0.f, 0.f};

#pragma unroll
    for (int t4 = 0; t4 < 4; ++t4) {  // s-pairs: s = 2*t4, 2*t4+1
      longx2 bp[4];
#pragma unroll
      for (int ni = 0; ni < 4; ++ni)
        bp[ni] = *reinterpret_cast<const longx2*>(
            &sB[bf][(ni * 16 + l15) * 256 + (((t4 * 4 + quad) ^ l15) << 4)]);
#pragma unroll
      for (int mi = 0; mi < 2; ++mi)
#pragma unroll
        for (int ni = 0; ni < 4; ++ni) {
          acc[mi][ni] = __builtin_amdgcn_mfma_f32_16x16x32_fp8_fp8(
              areg[2 * t4][mi], bp[ni].x, acc[mi][ni], 0, 0, 0);
          acc[mi][ni] = __builtin_amdgcn_mfma_f32_16x16x32_fp8_fp8(
              areg[2 * t4 + 1][mi], bp[ni].y, acc[mi][ni], 0, 0, 0);
        }
    }

    // rowexp += exp2(S_mfma)  (k2 pre-folded into A)
#pragma unroll
    for (int mi = 0; mi < 2; ++mi)
#pragma unroll
      for (int ni = 0; ni < 4; ++ni)
#pragma unroll
        for (int r = 0; r < 4; ++r)
          rowexp[mi * 4 + r] += __builtin_amdgcn_exp2f(acc[mi][ni][r]);

    __syncthreads();  // buffer reuse; prefetch had full compute to land
  }

  // ---- epilogue: one reduce + atomic per row slot ----
#pragma unroll
  for (int idx = 0; idx < 8; ++idx) {
    float se = rowexp[idx];
    se += __shfl_xor(se, 1);
    se += __shfl_xor(se, 2);
    se += __shfl_xor(se, 4);
    se += __shfl_xor(se, 8);
    if (l15 == 0) {
      const int row =
          rg * 128 + w * 32 + (idx >> 2) * 16 + quad * 4 + (idx & 3);
      atomicAdd(&sumexp[row], se);
    }
  }

  // ---- last block finalizes the loss ----
  if (tid == 0) {
    __threadfence();
    is_last = (atomicAdd(done, 1u) == NBLK - 1) ? 1u : 0u;
  }
  __syncthreads();
  if (is_last) {
    __threadfence();  // acquire: all blocks' sumexp atomics visible
    float lsum = 0.f;
    for (int i = tid; i < Nvec; i += 256) lsum += logf(sumexp[i]);
    // analytic P: per-channel batch sums from bpart partials, then dot
    float pp = 0.f;
#pragma unroll
    for (int b = 0; b < 8; ++b) {
      float sa = 0.f, sx = 0.f;
#pragma unroll 8
      for (int s = 0; s < 32; ++s) {
        sa += bpart[(size_t)(b * 32 + s) * 256 + tid];
        sx += bpart[(size_t)(256 + b * 32 + s) * 256 + tid];
      }
      pp += sa * sx;
    }
#pragma unroll
    for (int off = 1; off < 64; off <<= 1) {
      lsum += __shfl_xor(lsum, off);
      pp   += __shfl_xor(pp, off);
    }
    if ((tid & 63) == 0) { part4[w] = lsum; part4b[w] = pp; }
    __syncthreads();
    if (tid == 0) {
      float total_lse = 0.f, P = 0.f;
#pragma unroll
      for (int i = 0; i < 4; ++i) { total_lse += part4[i]; P += part4b[i]; }
      P *= 0.69314718056f;  // ln 2
      out[0] = -(P - 1024.0f * total_lse) / (8388608.0f + 1e-8f);
    }
  }
}

extern "C" void kernel_launch(void* const* d_in, const int* in_sizes, int n_in,
                              void* d_out, int out_size, void* d_ws,
                              size_t ws_size, hipStream_t stream) {
  const float* rgb = (const float*)d_in[0];
  const float* x   = (const float*)d_in[1];
  char* ws = (char*)d_ws;
  unsigned char* rgbq = (unsigned char*)ws;                             // 2 MiB
  unsigned char* xq   = (unsigned char*)(ws + (size_t)2 * 1024 * 1024); // 2 MiB
  float* sumexp = (float*)(ws + (size_t)4 * 1024 * 1024);  // 8192 floats
  float* bpart  = sumexp + Nvec;                           // 2*256*256 floats
  unsigned int* done = (unsigned int*)(bpart + 2 * 256 * 256);

  norm_kernel<<<dim3(256, 2), 256, 0, stream>>>(rgb, x, rgbq, xq, bpart,
                                                sumexp, done);
  gemm_loss_kernel<<<dim3(16, 64), 256, 0, stream>>>(rgbq, xq, sumexp, bpart,
                                                     done, (float*)d_out);
}

// Round 11
// 169.869 us; speedup vs baseline: 1.5161x; 1.5161x over previous
//
#include <hip/hip_runtime.h>
#include <hip/hip_bf16.h>

// CrossModalContrastiveLoss: B=8, C=256, H=W=32 -> N=8192 vectors of dim 256.
// loss = -( P - 1024 * sum_i log(sum_j exp(S_ij)) ) / 8388608,
// S = normalize(rgb) @ normalize(x)^T / 0.1.
// P analytic via bilinearity (verified r7-r10): P = ln2 * sum_b <rgbsum_b, xsum_b>
// (rgb side carries k2 = 10*log2(e) folded in at fp8 quantization, so
// S_mfma = k2*sim and exp(10 sim) = exp2(S_mfma)).
//
// Round-11 = round-10 layout with the register-liveness fix: B-fragments
// loaded ONE ni-pair at a time (8 regs peak, same as r9's proven-fit b64
// version) instead of all four longx2 at once (16 regs -> scratch spill,
// WRITE_SIZE 244 MB, r10's regression).

#define HWsz 1024
#define Cdim 256
#define Nvec 8192
#define CHW  (Cdim * HWsz)
#define NBLK 1024   // 16 strips x 64 rowgroups

typedef __attribute__((ext_vector_type(4))) float f32x4;
typedef __attribute__((ext_vector_type(2))) long longx2;

// Block = 32 vectors (one batch), 256 threads: part = t>>3 (channel chunk of
// 8), q = t&7 (vector quad). float4 loads: lane reads 16 B contiguous.
__global__ __launch_bounds__(256) void norm_kernel(
    const float* __restrict__ rgb, const float* __restrict__ x,
    unsigned char* __restrict__ rgbq, unsigned char* __restrict__ xq,
    float* __restrict__ bpart, float* __restrict__ sumexp,
    unsigned int* __restrict__ done) {
  __shared__ float ssp[32][33];
  __shared__ __align__(16) unsigned char tile[32][272];  // 272 = 16*17
  const int t = threadIdx.x;
  const int part = t >> 3;      // channel chunk (8 channels)
  const int q = t & 7;          // vector quad (4 vectors)
  const int isx = blockIdx.y;
  const float* src = isx ? x : rgb;
  unsigned char* dst = isx ? xq : rgbq;
  const int n0 = blockIdx.x * 32;
  const int b = n0 >> 10;       // batch, uniform per block
  const int hw0 = n0 & 1023;
  const float* p =
      src + (size_t)b * CHW + (size_t)part * 8 * HWsz + hw0 + q * 4;

  // init gemm-side buffers (safe: gemm is stream-ordered after this kernel)
  if (isx == 0) {
    if (t < 32) sumexp[blockIdx.x * 32 + t] = 0.f;
    if (blockIdx.x == 0 && t == 0) done[0] = 0u;
  }

  // va[k][j]: vector q*4+k, channel part*8+j
  float va[4][8];
  float ss[4] = {0.f, 0.f, 0.f, 0.f};
#pragma unroll
  for (int j = 0; j < 8; ++j) {
    const float4 v4 = *reinterpret_cast<const float4*>(p + (size_t)j * HWsz);
    va[0][j] = v4.x; va[1][j] = v4.y; va[2][j] = v4.z; va[3][j] = v4.w;
    ss[0] += v4.x * v4.x; ss[1] += v4.y * v4.y;
    ss[2] += v4.z * v4.z; ss[3] += v4.w * v4.w;
  }
#pragma unroll
  for (int k = 0; k < 4; ++k) ssp[part][q * 4 + k] = ss[k];
  __syncthreads();

  const float k2 = 14.4269504089f;  // (1/T) * log2(e), folded into rgb side
  const float topf = isx ? 1.0f : k2;
#pragma unroll
  for (int k = 0; k < 4; ++k) {
    float tot = 0.f;
#pragma unroll
    for (int p2 = 0; p2 < 32; ++p2) tot += ssp[p2][q * 4 + k];
    const float inv = topf / fmaxf(sqrtf(tot), 1e-12f);
    int pk0 = 0, pk1 = 0;
    pk0 = __builtin_amdgcn_cvt_pk_fp8_f32(va[0][0] * inv, va[0][1] * inv, pk0, false);
    pk0 = __builtin_amdgcn_cvt_pk_fp8_f32(va[0][2] * inv, va[0][3] * inv, pk0, true);
    pk1 = __builtin_amdgcn_cvt_pk_fp8_f32(va[0][4] * inv, va[0][5] * inv, pk1, false);
    pk1 = __builtin_amdgcn_cvt_pk_fp8_f32(va[0][6] * inv, va[0][7] * inv, pk1, true);
    // shift va rows down so va[0] is always the active k (keeps indices const)
#pragma unroll
    for (int kk = 0; kk < 3; ++kk)
#pragma unroll
      for (int j = 0; j < 8; ++j) va[kk][j] = va[kk + 1][j];
    unsigned int* wp =
        reinterpret_cast<unsigned int*>(&tile[q * 4 + k][part * 8]);
    wp[0] = (unsigned int)pk0;
    wp[1] = (unsigned int)pk1;
  }
  __syncthreads();

  // store: 2 passes x (16 rows x 256 B). xq gets the pair-interleaved K
  // permutation: unit u holds natural 8-B pieces p0 = 8*(u>>2)+(u&3), p0+4
  // (i.e. the s=2t and s=2t+1 fragments of quad u&3 -> b128-readable).
#pragma unroll
  for (int pass = 0; pass < 2; ++pass) {
    const int r = pass * 16 + (t >> 4);
    const int u = t & 15;
    if (isx) {
      const int p0 = 8 * (u >> 2) + (u & 3);
      longx2 val;
      val.x = *reinterpret_cast<const long*>(&tile[r][p0 * 8]);
      val.y = *reinterpret_cast<const long*>(&tile[r][(p0 + 4) * 8]);
      *reinterpret_cast<longx2*>(dst + (size_t)(n0 + r) * Cdim + u * 16) = val;
    } else {
      *reinterpret_cast<uint4*>(dst + (size_t)(n0 + r) * Cdim + u * 16) =
          *reinterpret_cast<const uint4*>(&tile[r][u * 16]);
    }
  }

  // per-channel column partial over this block's 32 vectors (dequantized =
  // exactly what the MFMA consumes). Plain store -> no init needed.
  float csum = 0.f;
#pragma unroll
  for (int r = 0; r < 32; ++r)
    csum += __builtin_amdgcn_cvt_f32_fp8((int)tile[r][t], 0);
  bpart[((size_t)isx * 256 + blockIdx.x) * 256 + t] = csum;
}

// Block = 4 waves, 128 rows x 512-col strip, fp8. A-panel 32 regs/wave.
// B: 8 chunks of 64 cols through double-buffered 2x16 KB LDS; staging slot
// vv holds permuted-global unit vv ^ (col&15); reader slot (4t4+quad)^l15
// -> one ds_read_b128 = the s=2t4 (lo) and s=2t4+1 (hi) fragments, 16-lane
// groups span all 16 unit-slots (conflict-free). 4 blocks/CU.
__global__ __launch_bounds__(256, 4) void gemm_loss_kernel(
    const unsigned char* __restrict__ A, const unsigned char* __restrict__ Bq,
    float* __restrict__ sumexp, const float* __restrict__ bpart,
    unsigned int* __restrict__ done, float* __restrict__ out) {
  __shared__ __align__(16) unsigned char sB[2][16384];
  __shared__ float part4[4], part4b[4];
  __shared__ unsigned int is_last;

  const int tid  = threadIdx.x;
  const int lane = tid & 63;
  const int w    = tid >> 6;      // wave 0..3 -> rows w*32..+32
  const int strip = blockIdx.x;   // 0..15 -> XCD-pinned (linear%8 == x%8)
  const int rg   = blockIdx.y;    // 0..63: rows rg*128..+128
  const int quad = lane >> 4;
  const int l15  = lane & 15;

  // ---- A fragments: direct global -> 32 regs/wave, once per block ----
  long areg[8][2];
#pragma unroll
  for (int mi = 0; mi < 2; ++mi) {
    const unsigned char* rp =
        A + (size_t)(rg * 128 + w * 32 + mi * 16 + l15) * Cdim + quad * 8;
#pragma unroll
    for (int s = 0; s < 8; ++s)
      areg[s][mi] = *reinterpret_cast<const long*>(rp + s * 32);
  }

  const int colOff = lane >> 4;   // staging: col within 4-col group
  const int vv = lane & 15;       // staging: LDS 16-B slot

  float rowexp[8];
#pragma unroll
  for (int i = 0; i < 8; ++i) rowexp[i] = 0.f;

  const unsigned char* Bbase = Bq + (size_t)strip * 512 * Cdim;

  // prefetch chunk 0
#pragma unroll
  for (int i = 0; i < 4; ++i) {
    const int colw = w * 16 + i * 4 + colOff;
    const unsigned char* gp =
        Bbase + (size_t)colw * Cdim + ((vv ^ (colw & 15)) * 16);
    unsigned char* lp = &sB[0][(w * 16 + i * 4) * 256];
    __builtin_amdgcn_global_load_lds(
        (const __attribute__((address_space(1))) void*)gp,
        (__attribute__((address_space(3))) void*)lp, 16, 0, 0);
  }
  __syncthreads();

  for (int c = 0; c < 8; ++c) {
    const int bf = c & 1;
    if (c < 7) {  // prefetch next chunk (overlaps this chunk's MFMA)
#pragma unroll
      for (int i = 0; i < 4; ++i) {
        const int colw = w * 16 + i * 4 + colOff;
        const unsigned char* gp =
            Bbase + (size_t)((c + 1) * 64 + colw) * Cdim +
            ((vv ^ (colw & 15)) * 16);
        unsigned char* lp = &sB[bf ^ 1][(w * 16 + i * 4) * 256];
        __builtin_amdgcn_global_load_lds(
            (const __attribute__((address_space(1))) void*)gp,
            (__attribute__((address_space(3))) void*)lp, 16, 0, 0);
      }
    }

    f32x4 acc[2][4];
#pragma unroll
    for (int mi = 0; mi < 2; ++mi)
#pragma unroll
      for (int ni = 0; ni < 4; ++ni) acc[mi][ni] = (f32x4){0.f, 0.f, 0.f, 0.f};

#pragma unroll
    for (int t4 = 0; t4 < 4; ++t4) {  // s-pairs: s = 2*t4, 2*t4+1
#pragma unroll
      for (int np = 0; np < 2; ++np) {  // ni pairs: 8 live B regs max
        const longx2 b0 = *reinterpret_cast<const longx2*>(
            &sB[bf][((np * 2) * 16 + l15) * 256 + (((t4 * 4 + quad) ^ l15) << 4)]);
        const longx2 b1 = *reinterpret_cast<const longx2*>(
            &sB[bf][((np * 2 + 1) * 16 + l15) * 256 + (((t4 * 4 + quad) ^ l15) << 4)]);
#pragma unroll
        for (int mi = 0; mi < 2; ++mi) {
          acc[mi][np * 2] = __builtin_amdgcn_mfma_f32_16x16x32_fp8_fp8(
              areg[2 * t4][mi], b0.x, acc[mi][np * 2], 0, 0, 0);
          acc[mi][np * 2] = __builtin_amdgcn_mfma_f32_16x16x32_fp8_fp8(
              areg[2 * t4 + 1][mi], b0.y, acc[mi][np * 2], 0, 0, 0);
          acc[mi][np * 2 + 1] = __builtin_amdgcn_mfma_f32_16x16x32_fp8_fp8(
              areg[2 * t4][mi], b1.x, acc[mi][np * 2 + 1], 0, 0, 0);
          acc[mi][np * 2 + 1] = __builtin_amdgcn_mfma_f32_16x16x32_fp8_fp8(
              areg[2 * t4 + 1][mi], b1.y, acc[mi][np * 2 + 1], 0, 0, 0);
        }
      }
    }

    // rowexp += exp2(S_mfma)  (k2 pre-folded into A)
#pragma unroll
    for (int mi = 0; mi < 2; ++mi)
#pragma unroll
      for (int ni = 0; ni < 4; ++ni)
#pragma unroll
        for (int r = 0; r < 4; ++r)
          rowexp[mi * 4 + r] += __builtin_amdgcn_exp2f(acc[mi][ni][r]);

    __syncthreads();  // buffer reuse; prefetch had full compute to land
  }

  // ---- epilogue: one reduce + atomic per row slot ----
#pragma unroll
  for (int idx = 0; idx < 8; ++idx) {
    float se = rowexp[idx];
    se += __shfl_xor(se, 1);
    se += __shfl_xor(se, 2);
    se += __shfl_xor(se, 4);
    se += __shfl_xor(se, 8);
    if (l15 == 0) {
      const int row =
          rg * 128 + w * 32 + (idx >> 2) * 16 + quad * 4 + (idx & 3);
      atomicAdd(&sumexp[row], se);
    }
  }

  // ---- last block finalizes the loss ----
  if (tid == 0) {
    __threadfence();
    is_last = (atomicAdd(done, 1u) == NBLK - 1) ? 1u : 0u;
  }
  __syncthreads();
  if (is_last) {
    __threadfence();  // acquire: all blocks' sumexp atomics visible
    float lsum = 0.f;
    for (int i = tid; i < Nvec; i += 256) lsum += logf(sumexp[i]);
    // analytic P: per-channel batch sums from bpart partials, then dot
    float pp = 0.f;
#pragma unroll
    for (int b = 0; b < 8; ++b) {
      float sa = 0.f, sx = 0.f;
#pragma unroll 8
      for (int s = 0; s < 32; ++s) {
        sa += bpart[(size_t)(b * 32 + s) * 256 + tid];
        sx += bpart[(size_t)(256 + b * 32 + s) * 256 + tid];
      }
      pp += sa * sx;
    }
#pragma unroll
    for (int off = 1; off < 64; off <<= 1) {
      lsum += __shfl_xor(lsum, off);
      pp   += __shfl_xor(pp, off);
    }
    if ((tid & 63) == 0) { part4[tid >> 6] = lsum; part4b[tid >> 6] = pp; }
    __syncthreads();
    if (tid == 0) {
      float total_lse = 0.f, P = 0.f;
#pragma unroll
      for (int i = 0; i < 4; ++i) { total_lse += part4[i]; P += part4b[i]; }
      P *= 0.69314718056f;  // ln 2
      out[0] = -(P - 1024.0f * total_lse) / (8388608.0f + 1e-8f);
    }
  }
}

extern "C" void kernel_launch(void* const* d_in, const int* in_sizes, int n_in,
                              void* d_out, int out_size, void* d_ws,
                              size_t ws_size, hipStream_t stream) {
  const float* rgb = (const float*)d_in[0];
  const float* x   = (const float*)d_in[1];
  char* ws = (char*)d_ws;
  unsigned char* rgbq = (unsigned char*)ws;                             // 2 MiB
  unsigned char* xq   = (unsigned char*)(ws + (size_t)2 * 1024 * 1024); // 2 MiB
  float* sumexp = (float*)(ws + (size_t)4 * 1024 * 1024);  // 8192 floats
  float* bpart  = sumexp + Nvec;                           // 2*256*256 floats
  unsigned int* done = (unsigned int*)(bpart + 2 * 256 * 256);

  norm_kernel<<<dim3(256, 2), 256, 0, stream>>>(rgb, x, rgbq, xq, bpart,
                                                sumexp, done);
  gemm_loss_kernel<<<dim3(16, 64), 256, 0, stream>>>(rgbq, xq, sumexp, bpart,
                                                     done, (float*)d_out);
}

// Round 12
// 125.364 us; speedup vs baseline: 2.0543x; 1.3550x over previous
//
#include <hip/hip_runtime.h>
#include <hip/hip_bf16.h>

// CrossModalContrastiveLoss: B=8, C=256, H=W=32 -> N=8192 vectors of dim 256.
// loss = -( P - 1024 * sum_i log(sum_j exp(S_ij)) ) / 8388608,
// S = normalize(rgb) @ normalize(x)^T / 0.1.
// P analytic via bilinearity (verified r7-r11): P = ln2 * sum_b <rgbsum_b, xsum_b>
// (rgb side carries k2 = 10*log2(e) folded in at fp8 quantization, so
// S_mfma = k2*sim and exp(10 sim) = exp2(S_mfma)).
//
// Round-12 = RECOVERY: r9's proven fp8 gemm (53 us, b64 LDS reads, no spill)
// + r11's norm (float4 loads, init folded, bpart partials) with NATURAL xq
// layout + prefetch-before-A-loads prologue reorder. The b128 experiments
// (r10/r11) spilled AGPR-side scratch at the 128-reg/4-block budget and are
// abandoned.

#define HWsz 1024
#define Cdim 256
#define Nvec 8192
#define CHW  (Cdim * HWsz)
#define NBLK 1024   // 16 strips x 64 rowgroups

typedef __attribute__((ext_vector_type(4))) float f32x4;

// Block = 32 vectors (one batch), 256 threads: part = t>>3 (channel chunk of
// 8), q = t&7 (vector quad). float4 loads: lane reads 16 B contiguous.
__global__ __launch_bounds__(256) void norm_kernel(
    const float* __restrict__ rgb, const float* __restrict__ x,
    unsigned char* __restrict__ rgbq, unsigned char* __restrict__ xq,
    float* __restrict__ bpart, float* __restrict__ sumexp,
    unsigned int* __restrict__ done) {
  __shared__ float ssp[32][33];
  __shared__ __align__(16) unsigned char tile[32][272];  // 272 = 16*17
  const int t = threadIdx.x;
  const int part = t >> 3;      // channel chunk (8 channels)
  const int q = t & 7;          // vector quad (4 vectors)
  const int isx = blockIdx.y;
  const float* src = isx ? x : rgb;
  unsigned char* dst = isx ? xq : rgbq;
  const int n0 = blockIdx.x * 32;
  const int b = n0 >> 10;       // batch, uniform per block
  const int hw0 = n0 & 1023;
  const float* p =
      src + (size_t)b * CHW + (size_t)part * 8 * HWsz + hw0 + q * 4;

  // init gemm-side buffers (safe: gemm is stream-ordered after this kernel)
  if (isx == 0) {
    if (t < 32) sumexp[blockIdx.x * 32 + t] = 0.f;
    if (blockIdx.x == 0 && t == 0) done[0] = 0u;
  }

  // va[k][j]: vector q*4+k, channel part*8+j
  float va[4][8];
  float ss[4] = {0.f, 0.f, 0.f, 0.f};
#pragma unroll
  for (int j = 0; j < 8; ++j) {
    const float4 v4 = *reinterpret_cast<const float4*>(p + (size_t)j * HWsz);
    va[0][j] = v4.x; va[1][j] = v4.y; va[2][j] = v4.z; va[3][j] = v4.w;
    ss[0] += v4.x * v4.x; ss[1] += v4.y * v4.y;
    ss[2] += v4.z * v4.z; ss[3] += v4.w * v4.w;
  }
#pragma unroll
  for (int k = 0; k < 4; ++k) ssp[part][q * 4 + k] = ss[k];
  __syncthreads();

  const float k2 = 14.4269504089f;  // (1/T) * log2(e), folded into rgb side
  const float topf = isx ? 1.0f : k2;
#pragma unroll
  for (int k = 0; k < 4; ++k) {
    float tot = 0.f;
#pragma unroll
    for (int p2 = 0; p2 < 32; ++p2) tot += ssp[p2][q * 4 + k];
    const float inv = topf / fmaxf(sqrtf(tot), 1e-12f);
    int pk0 = 0, pk1 = 0;
    pk0 = __builtin_amdgcn_cvt_pk_fp8_f32(va[0][0] * inv, va[0][1] * inv, pk0, false);
    pk0 = __builtin_amdgcn_cvt_pk_fp8_f32(va[0][2] * inv, va[0][3] * inv, pk0, true);
    pk1 = __builtin_amdgcn_cvt_pk_fp8_f32(va[0][4] * inv, va[0][5] * inv, pk1, false);
    pk1 = __builtin_amdgcn_cvt_pk_fp8_f32(va[0][6] * inv, va[0][7] * inv, pk1, true);
    // shift va rows down so va[0] is always the active k (keeps indices const)
#pragma unroll
    for (int kk = 0; kk < 3; ++kk)
#pragma unroll
      for (int j = 0; j < 8; ++j) va[kk][j] = va[kk + 1][j];
    unsigned int* wp =
        reinterpret_cast<unsigned int*>(&tile[q * 4 + k][part * 8]);
    wp[0] = (unsigned int)pk0;
    wp[1] = (unsigned int)pk1;
  }
  __syncthreads();

  // coalesced store: 2 passes x (16 rows x 256 B), natural (N,C) layout
#pragma unroll
  for (int pass = 0; pass < 2; ++pass) {
    const int r = pass * 16 + (t >> 4);
    const int u = t & 15;
    *reinterpret_cast<uint4*>(dst + (size_t)(n0 + r) * Cdim + u * 16) =
        *reinterpret_cast<const uint4*>(&tile[r][u * 16]);
  }

  // per-channel column partial over this block's 32 vectors (dequantized =
  // exactly what the MFMA consumes). Plain store -> no init needed.
  float csum = 0.f;
#pragma unroll
  for (int r = 0; r < 32; ++r)
    csum += __builtin_amdgcn_cvt_f32_fp8((int)tile[r][t], 0);
  bpart[((size_t)isx * 256 + blockIdx.x) * 256 + t] = csum;
}

// Block = 4 waves, 128 rows x 512-col strip, fp8 (r9-proven). A-panel 32
// regs/wave. B: 8 chunks of 64 cols through double-buffered 2x16 KB LDS.
// fp8 LDS swizzle (16-B staging granule): col's 16 units placed at
//   phys(unit) = ((unit>>1) ^ (col&7) ^ ((unit&1)<<2)) + ((unit&1)<<3),
// inverted on the global address side to respect global_load_lds's
// wave-uniform-base + lane*16 constraint. Reads are b64 (2-way residual
// aliasing inherent to pair-preserving staging; measured +4 cyc/read floor).
// 4 blocks/CU.
__global__ __launch_bounds__(256, 4) void gemm_loss_kernel(
    const unsigned char* __restrict__ A, const unsigned char* __restrict__ Bq,
    float* __restrict__ sumexp, const float* __restrict__ bpart,
    unsigned int* __restrict__ done, float* __restrict__ out) {
  __shared__ __align__(16) unsigned char sB[2][16384];
  __shared__ float part4[4], part4b[4];
  __shared__ unsigned int is_last;

  const int tid  = threadIdx.x;
  const int lane = tid & 63;
  const int w    = tid >> 6;      // wave 0..3 -> rows w*32..+32
  const int strip = blockIdx.x;   // 0..15: cols strip*512..+512 (XCD-pinned)
  const int rg   = blockIdx.y;    // 0..63: rows rg*128..+128
  const int quad = lane >> 4;
  const int l15  = lane & 15;

  // staging lane constants: lane = c4*16 + u writes (col base+c4, slot u)
  const int u_  = l15;
  const int c4  = quad;
  const int gx  = (u_ & 7) ^ ((u_ >> 3) << 2);
  const int godd = u_ >> 3;   // global unit parity this slot holds
  // reader lane constants
  const int sxor = (l15 & 7) ^ ((quad >> 1) << 2);
  const int boff = ((quad >> 1) << 7) + ((quad & 1) << 3);

  const unsigned char* Bbase = Bq + (size_t)strip * 512 * Cdim;

  // prefetch chunk 0 FIRST (staging starts before the A-reg loads issue)
#pragma unroll
  for (int i = 0; i < 4; ++i) {
    const int colw = w * 16 + i * 4 + c4;
    const unsigned char* gp = Bbase + (size_t)colw * Cdim +
                              32 * (gx ^ (colw & 7)) + godd * 16;
    unsigned char* lp = &sB[0][(w * 16 + i * 4) * 256];
    __builtin_amdgcn_global_load_lds(
        (const __attribute__((address_space(1))) void*)gp,
        (__attribute__((address_space(3))) void*)lp, 16, 0, 0);
  }

  // ---- A fragments: direct global -> 32 regs/wave, once per block ----
  long areg[8][2];
#pragma unroll
  for (int mi = 0; mi < 2; ++mi) {
    const unsigned char* rp =
        A + (size_t)(rg * 128 + w * 32 + mi * 16 + l15) * Cdim + quad * 8;
#pragma unroll
    for (int s = 0; s < 8; ++s)
      areg[s][mi] = *reinterpret_cast<const long*>(rp + s * 32);
  }

  float rowexp[8];
#pragma unroll
  for (int i = 0; i < 8; ++i) rowexp[i] = 0.f;

  __syncthreads();

  for (int c = 0; c < 8; ++c) {
    const int bf = c & 1;
    if (c < 7) {  // prefetch next chunk (overlaps this chunk's MFMA)
#pragma unroll
      for (int i = 0; i < 4; ++i) {
        const int colw = w * 16 + i * 4 + c4;
        const unsigned char* gp = Bbase + (size_t)((c + 1) * 64 + colw) * Cdim +
                                  32 * (gx ^ (colw & 7)) + godd * 16;
        unsigned char* lp = &sB[bf ^ 1][(w * 16 + i * 4) * 256];
        __builtin_amdgcn_global_load_lds(
            (const __attribute__((address_space(1))) void*)gp,
            (__attribute__((address_space(3))) void*)lp, 16, 0, 0);
      }
    }

    f32x4 acc[2][4];
#pragma unroll
    for (int mi = 0; mi < 2; ++mi)
#pragma unroll
      for (int ni = 0; ni < 4; ++ni) acc[mi][ni] = (f32x4){0.f, 0.f, 0.f, 0.f};

#pragma unroll
    for (int s = 0; s < 8; ++s) {
      const int soff = ((s ^ sxor) << 4) + boff;
      long bfr[4];
#pragma unroll
      for (int ni = 0; ni < 4; ++ni)
        bfr[ni] = *reinterpret_cast<const long*>(
            &sB[bf][(ni * 16 + l15) * 256 + soff]);
#pragma unroll
      for (int mi = 0; mi < 2; ++mi)
#pragma unroll
        for (int ni = 0; ni < 4; ++ni)
          acc[mi][ni] = __builtin_amdgcn_mfma_f32_16x16x32_fp8_fp8(
              areg[s][mi], bfr[ni], acc[mi][ni], 0, 0, 0);
    }

    // rowexp += exp2(S_mfma)  (k2 pre-folded into A)
#pragma unroll
    for (int mi = 0; mi < 2; ++mi)
#pragma unroll
      for (int ni = 0; ni < 4; ++ni)
#pragma unroll
        for (int r = 0; r < 4; ++r)
          rowexp[mi * 4 + r] += __builtin_amdgcn_exp2f(acc[mi][ni][r]);

    __syncthreads();  // buffer reuse; prefetch had full compute to land
  }

  // ---- epilogue: one reduce + atomic per row slot ----
#pragma unroll
  for (int idx = 0; idx < 8; ++idx) {
    float se = rowexp[idx];
    se += __shfl_xor(se, 1);
    se += __shfl_xor(se, 2);
    se += __shfl_xor(se, 4);
    se += __shfl_xor(se, 8);
    if (l15 == 0) {
      const int row =
          rg * 128 + w * 32 + (idx >> 2) * 16 + quad * 4 + (idx & 3);
      atomicAdd(&sumexp[row], se);
    }
  }

  // ---- last block finalizes the loss ----
  if (tid == 0) {
    __threadfence();
    is_last = (atomicAdd(done, 1u) == NBLK - 1) ? 1u : 0u;
  }
  __syncthreads();
  if (is_last) {
    __threadfence();  // acquire: all blocks' sumexp atomics visible
    float lsum = 0.f;
    for (int i = tid; i < Nvec; i += 256) lsum += logf(sumexp[i]);
    // analytic P: per-channel batch sums from bpart partials, then dot
    float pp = 0.f;
#pragma unroll
    for (int b = 0; b < 8; ++b) {
      float sa = 0.f, sx = 0.f;
#pragma unroll 8
      for (int s = 0; s < 32; ++s) {
        sa += bpart[(size_t)(b * 32 + s) * 256 + tid];
        sx += bpart[(size_t)(256 + b * 32 + s) * 256 + tid];
      }
      pp += sa * sx;
    }
#pragma unroll
    for (int off = 1; off < 64; off <<= 1) {
      lsum += __shfl_xor(lsum, off);
      pp   += __shfl_xor(pp, off);
    }
    if ((tid & 63) == 0) { part4[tid >> 6] = lsum; part4b[tid >> 6] = pp; }
    __syncthreads();
    if (tid == 0) {
      float total_lse = 0.f, P = 0.f;
#pragma unroll
      for (int i = 0; i < 4; ++i) { total_lse += part4[i]; P += part4b[i]; }
      P *= 0.69314718056f;  // ln 2
      out[0] = -(P - 1024.0f * total_lse) / (8388608.0f + 1e-8f);
    }
  }
}

extern "C" void kernel_launch(void* const* d_in, const int* in_sizes, int n_in,
                              void* d_out, int out_size, void* d_ws,
                              size_t ws_size, hipStream_t stream) {
  const float* rgb = (const float*)d_in[0];
  const float* x   = (const float*)d_in[1];
  char* ws = (char*)d_ws;
  unsigned char* rgbq = (unsigned char*)ws;                             // 2 MiB
  unsigned char* xq   = (unsigned char*)(ws + (size_t)2 * 1024 * 1024); // 2 MiB
  float* sumexp = (float*)(ws + (size_t)4 * 1024 * 1024);  // 8192 floats
  float* bpart  = sumexp + Nvec;                           // 2*256*256 floats
  unsigned int* done = (unsigned int*)(bpart + 2 * 256 * 256);

  norm_kernel<<<dim3(256, 2), 256, 0, stream>>>(rgb, x, rgbq, xq, bpart,
                                                sumexp, done);
  gemm_loss_kernel<<<dim3(16, 64), 256, 0, stream>>>(rgbq, xq, sumexp, bpart,
                                                     done, (float*)d_out);
}